// Round 2
// baseline (284.873 us; speedup 1.0000x reference)
//
#include <hip/hip_runtime.h>

// QAttentionLayer: out[..., i] = prod_{j<=i} cos(x_j)*cos(w_j), rows of 10 fp32.
// Memory-bound streaming kernel (335 MB total traffic -> ~53 us floor).
// Rows are 40 B (not 16B-aligned) -> stage 512 rows/block through LDS with
// coalesced float4 loads/stores; process rows in-place from LDS.
// fp32 dtypes per the reference (round-1 NaN forensics: fp32-as-bf16 read is
// the only consistent NaN source; bf16-writes-read-as-fp32 would be finite).

#define BLOCK 256
#define ROWS_PER_THREAD 2
#define ROWS_PER_BLOCK (BLOCK * ROWS_PER_THREAD)          // 512 rows
#define NQ 10
#define WORDS_PER_BLOCK (ROWS_PER_BLOCK * NQ)             // 5120 fp32 = 20480 B
#define U4_PER_BLOCK (WORDS_PER_BLOCK / 4)                // 1280 float4
#define U4_PER_THREAD (U4_PER_BLOCK / BLOCK)              // 5

__global__ __launch_bounds__(BLOCK) void qcircuit_kernel(
    const float* __restrict__ x,
    const float* __restrict__ w,
    float* __restrict__ out,
    int n_rows)
{
    __shared__ float4 buf4[U4_PER_BLOCK];
    float* bufw = (float*)buf4;

    const int tid = threadIdx.x;
    const long long block_row0 = (long long)blockIdx.x * ROWS_PER_BLOCK;
    const long long total_u4   = ((long long)n_rows * NQ) / 4;
    const long long u4_base    = (long long)blockIdx.x * U4_PER_BLOCK;
    const float4* __restrict__ gin  = (const float4*)x;
    float4* __restrict__       gout = (float4*)out;

    // ---- coalesced global -> LDS stage (16 B/lane) ----
    #pragma unroll
    for (int k = 0; k < U4_PER_THREAD; ++k) {
        long long gi = u4_base + (long long)(k * BLOCK + tid);
        if (gi < total_u4) buf4[k * BLOCK + tid] = gin[gi];
    }

    // cos(weights): uniform (scalar) loads, amortized over 2 rows
    float cw[NQ];
    #pragma unroll
    for (int j = 0; j < NQ; ++j) cw[j] = __cosf(w[j]);

    __syncthreads();

    // ---- process 2 rows/thread in-place in LDS (word stride 10) ----
    #pragma unroll
    for (int m = 0; m < ROWS_PER_THREAD; ++m) {
        const int r = tid + m * BLOCK;                    // block-local row
        if (block_row0 + r < n_rows) {
            float v[NQ];
            #pragma unroll
            for (int j = 0; j < NQ; ++j) v[j] = bufw[r * NQ + j];
            float p = 1.0f;
            #pragma unroll
            for (int j = 0; j < NQ; ++j) {
                p *= __cosf(v[j]) * cw[j];
                v[j] = p;
            }
            #pragma unroll
            for (int j = 0; j < NQ; ++j) bufw[r * NQ + j] = v[j];
        }
    }

    __syncthreads();

    // ---- coalesced LDS -> global store (16 B/lane) ----
    #pragma unroll
    for (int k = 0; k < U4_PER_THREAD; ++k) {
        long long gi = u4_base + (long long)(k * BLOCK + tid);
        if (gi < total_u4) gout[gi] = buf4[k * BLOCK + tid];
    }
}

extern "C" void kernel_launch(void* const* d_in, const int* in_sizes, int n_in,
                              void* d_out, int out_size, void* d_ws, size_t ws_size,
                              hipStream_t stream) {
    const float* x = (const float*)d_in[0];
    const float* w = (const float*)d_in[1];
    float* out = (float*)d_out;

    const int n_elem = in_sizes[0];
    const int n_rows = n_elem / NQ;
    const int blocks = (n_rows + ROWS_PER_BLOCK - 1) / ROWS_PER_BLOCK;

    hipLaunchKernelGGL(qcircuit_kernel, dim3(blocks), dim3(BLOCK), 0, stream,
                       x, w, out, n_rows);
}